// Round 5
// baseline (242.596 us; speedup 1.0000x reference)
//
#include <hip/hip_runtime.h>
#include <math.h>

#define BUF_SIZE 1000
// Mirror the reference's constants exactly (LN2 truncated to 0.693147).
#define TARGET_LOG_MEAN 7.6438561897747395f            // float(np.log2(200.0))
#define TARGET_LOG_STD  (40.0f / (200.0f * 0.693147f)) // 0.288538...

// Native clang vector type — required by __builtin_nontemporal_store
// (HIP's float4 is a struct and is rejected).
typedef float v4f __attribute__((ext_vector_type(4)));

// ---------------------------------------------------------------------------
// Fused kernel:
//   Phase 1 (redundant per block): scan backward from the tail, identify the
//     last min(1000, n_valid) valid pitches, accumulate sum/sumsq of log2 in
//     double, derive scale/bias into LDS. ~2 chunks of 1024 elems => ~8 KB of
//     tail reads per block, L2/LLC-served after the first arrivals.
//   Phase 2: grid-stride streaming transform, manually unrolled x4 so each
//     thread keeps 4 independent 16B loads in flight (latency hiding);
//     nontemporal stores so output write-allocate doesn't evict the
//     LLC-resident input.
//     out = p>0 ? exp2(log2(p)*scale + bias) : 0
// ---------------------------------------------------------------------------
__global__ void fused_kernel(const float* __restrict__ pitch, long long n,
                             float* __restrict__ out) {
    const int tid = threadIdx.x;          // block = 256 threads
    __shared__ int s_cnt[256];
    __shared__ double s_red[256];
    __shared__ float s_sb[2];

    // ---------------- Phase 1: tail stats ----------------
    double sum = 0.0, sumsq = 0.0;
    long long count_so_far = 0;

    const long long nchunks = (n + 1023) >> 10;   // 1024-element chunks
    for (long long c = nchunks - 1; c >= 0; --c) {
        const long long base = (c << 10) + (long long)tid * 4;
        float v[4];
        int valid[4];
        int cnt = 0;
#pragma unroll
        for (int j = 0; j < 4; ++j) {
            const long long idx = base + j;
            const float p = (idx < n) ? pitch[idx] : 0.0f;
            v[j] = p;
            valid[j] = (p > 0.0f) ? 1 : 0;
            cnt += valid[j];
        }

        // Block-wide inclusive scan of per-thread valid counts (Hillis-Steele).
        s_cnt[tid] = cnt;
        __syncthreads();
        for (int off = 1; off < 256; off <<= 1) {
            const int mine = s_cnt[tid];
            const int add = (tid >= off) ? s_cnt[tid - off] : 0;
            __syncthreads();
            s_cnt[tid] = mine + add;
            __syncthreads();
        }
        const int incl = s_cnt[tid];
        const int total = s_cnt[255];
        const int suff_after = total - incl;   // valid elems in higher threads

        // Walk my 4 elements newest-to-oldest, assigning global reverse ranks.
        int r = 0;
#pragma unroll
        for (int j = 3; j >= 0; --j) {
            if (valid[j]) {
                const long long rev = count_so_far + suff_after + r;
                if (rev < BUF_SIZE) {
                    const double lp = (double)__log2f(v[j]);
                    sum += lp;
                    sumsq += lp * lp;
                }
                r++;
            }
        }

        count_so_far += total;
        __syncthreads();                 // s_cnt reused next iteration
        if (count_so_far >= BUF_SIZE) break;   // uniform across block
    }

    // Block reduction of sum and sumsq (LDS tree).
    s_red[tid] = sum;
    __syncthreads();
    for (int off = 128; off > 0; off >>= 1) {
        if (tid < off) s_red[tid] += s_red[tid + off];
        __syncthreads();
    }
    const double tsum = s_red[0];
    __syncthreads();
    s_red[tid] = sumsq;
    __syncthreads();
    for (int off = 128; off > 0; off >>= 1) {
        if (tid < off) s_red[tid] += s_red[tid + off];
        __syncthreads();
    }
    const double tsumsq = s_red[0];

    if (tid == 0) {
        const long long count = (count_so_far < BUF_SIZE) ? count_so_far : BUF_SIZE;
        float mean, stdv;
        if (count == 0) {
            mean = 0.0f;
            stdv = 1.0f;
        } else {
            mean = (float)(tsum / (double)count);
            if (count > 1) {
                double var = (tsumsq - tsum * tsum / (double)count) /
                             (double)(count - 1);
                if (var < 0.0) var = 0.0;
                stdv = (float)sqrt(var);
            } else {
                stdv = 1.0f;
            }
        }
        if (stdv < 1e-7f) stdv = 1e-7f;
        const float scale = TARGET_LOG_STD / stdv;
        s_sb[0] = scale;
        s_sb[1] = TARGET_LOG_MEAN - mean * scale;
    }
    __syncthreads();

    const float scale = s_sb[0];
    const float bias = s_sb[1];

    // ---------------- Phase 2: streaming transform ----------------
    const long long n4 = n >> 2;
    const long long gid = (long long)blockIdx.x * blockDim.x + tid;
    const long long stride = (long long)gridDim.x * blockDim.x;
    const v4f* __restrict__ in4 = (const v4f*)pitch;
    v4f* __restrict__ out4 = (v4f*)out;

    long long k = gid;
    // Unrolled x4: 4 independent loads in flight before any compute.
    for (; k + 3 * stride < n4; k += 4 * stride) {
        const v4f p0 = in4[k];
        const v4f p1 = in4[k + stride];
        const v4f p2 = in4[k + 2 * stride];
        const v4f p3 = in4[k + 3 * stride];

        v4f o0, o1, o2, o3;
        o0.x = (p0.x > 0.0f) ? exp2f(fmaf(__log2f(p0.x), scale, bias)) : 0.0f;
        o0.y = (p0.y > 0.0f) ? exp2f(fmaf(__log2f(p0.y), scale, bias)) : 0.0f;
        o0.z = (p0.z > 0.0f) ? exp2f(fmaf(__log2f(p0.z), scale, bias)) : 0.0f;
        o0.w = (p0.w > 0.0f) ? exp2f(fmaf(__log2f(p0.w), scale, bias)) : 0.0f;
        o1.x = (p1.x > 0.0f) ? exp2f(fmaf(__log2f(p1.x), scale, bias)) : 0.0f;
        o1.y = (p1.y > 0.0f) ? exp2f(fmaf(__log2f(p1.y), scale, bias)) : 0.0f;
        o1.z = (p1.z > 0.0f) ? exp2f(fmaf(__log2f(p1.z), scale, bias)) : 0.0f;
        o1.w = (p1.w > 0.0f) ? exp2f(fmaf(__log2f(p1.w), scale, bias)) : 0.0f;
        o2.x = (p2.x > 0.0f) ? exp2f(fmaf(__log2f(p2.x), scale, bias)) : 0.0f;
        o2.y = (p2.y > 0.0f) ? exp2f(fmaf(__log2f(p2.y), scale, bias)) : 0.0f;
        o2.z = (p2.z > 0.0f) ? exp2f(fmaf(__log2f(p2.z), scale, bias)) : 0.0f;
        o2.w = (p2.w > 0.0f) ? exp2f(fmaf(__log2f(p2.w), scale, bias)) : 0.0f;
        o3.x = (p3.x > 0.0f) ? exp2f(fmaf(__log2f(p3.x), scale, bias)) : 0.0f;
        o3.y = (p3.y > 0.0f) ? exp2f(fmaf(__log2f(p3.y), scale, bias)) : 0.0f;
        o3.z = (p3.z > 0.0f) ? exp2f(fmaf(__log2f(p3.z), scale, bias)) : 0.0f;
        o3.w = (p3.w > 0.0f) ? exp2f(fmaf(__log2f(p3.w), scale, bias)) : 0.0f;

        __builtin_nontemporal_store(o0, &out4[k]);
        __builtin_nontemporal_store(o1, &out4[k + stride]);
        __builtin_nontemporal_store(o2, &out4[k + 2 * stride]);
        __builtin_nontemporal_store(o3, &out4[k + 3 * stride]);
    }
    // Remainder grid-stride iterations.
    for (; k < n4; k += stride) {
        const v4f p = in4[k];
        v4f o;
        o.x = (p.x > 0.0f) ? exp2f(fmaf(__log2f(p.x), scale, bias)) : 0.0f;
        o.y = (p.y > 0.0f) ? exp2f(fmaf(__log2f(p.y), scale, bias)) : 0.0f;
        o.z = (p.z > 0.0f) ? exp2f(fmaf(__log2f(p.z), scale, bias)) : 0.0f;
        o.w = (p.w > 0.0f) ? exp2f(fmaf(__log2f(p.w), scale, bias)) : 0.0f;
        __builtin_nontemporal_store(o, &out4[k]);
    }

    // Scalar tail (n not divisible by 4).
    const long long tail_start = n4 << 2;
    for (long long t = tail_start + gid; t < n; t += stride) {
        const float p = pitch[t];
        out[t] = (p > 0.0f) ? exp2f(fmaf(__log2f(p), scale, bias)) : 0.0f;
    }
}

extern "C" void kernel_launch(void* const* d_in, const int* in_sizes, int n_in,
                              void* d_out, int out_size, void* d_ws, size_t ws_size,
                              hipStream_t stream) {
    const float* pitch = (const float*)d_in[0];
    float* out = (float*)d_out;
    const long long n = (long long)in_sizes[0];

    // 2048 blocks = 8 blocks/CU on 256 CUs: fully co-resident, each thread
    // streams ~16 float4s at n = 2^25 (4 unrolled iterations of 4).
    int blocks = 2048;
    const long long n4 = n >> 2;
    const long long needed = (n4 + 255) / 256;
    if ((long long)blocks > needed) blocks = (int)(needed > 0 ? needed : 1);

    fused_kernel<<<blocks, 256, 0, stream>>>(pitch, n, out);
}

// Round 6
// 225.927 us; speedup vs baseline: 1.0738x; 1.0738x over previous
//
#include <hip/hip_runtime.h>
#include <math.h>

#define BUF_SIZE 1000
// Mirror the reference's constants exactly (LN2 truncated to 0.693147).
#define TARGET_LOG_MEAN 7.6438561897747395f            // float(np.log2(200.0))
#define TARGET_LOG_STD  (40.0f / (200.0f * 0.693147f)) // 0.288538...

// ---------------------------------------------------------------------------
// Kernel 1: tail stats. One block, 256 threads, 4096-element chunks
// (16 elems/thread) scanning backward; one chunk usually holds >=1000 valid
// pitches (~80% density), so the loop typically runs once.
// Emits scale/bias to d_ws.
// ---------------------------------------------------------------------------
__global__ void stats_kernel(const float* __restrict__ pitch, long long n,
                             float* __restrict__ stats) {
    const int tid = threadIdx.x;
    __shared__ int s_cnt[256];
    __shared__ double s_red[256];

    double sum = 0.0, sumsq = 0.0;
    long long count_so_far = 0;

    const long long nchunks = (n + 4095) >> 12;   // 4096-element chunks
    for (long long c = nchunks - 1; c >= 0; --c) {
        const long long base = (c << 12) + (long long)tid * 16;
        float v[16];
        int valid[16];
        int cnt = 0;
        if (base + 15 < n) {
#pragma unroll
            for (int q = 0; q < 4; ++q) {
                const float4 p4 = *(const float4*)(pitch + base + 4 * q);
                v[4 * q + 0] = p4.x; v[4 * q + 1] = p4.y;
                v[4 * q + 2] = p4.z; v[4 * q + 3] = p4.w;
            }
        } else {
#pragma unroll
            for (int j = 0; j < 16; ++j) {
                const long long idx = base + j;
                v[j] = (idx < n) ? pitch[idx] : 0.0f;
            }
        }
#pragma unroll
        for (int j = 0; j < 16; ++j) {
            valid[j] = (v[j] > 0.0f) ? 1 : 0;
            cnt += valid[j];
        }

        // Block-wide inclusive scan of per-thread valid counts (Hillis-Steele).
        s_cnt[tid] = cnt;
        __syncthreads();
        for (int off = 1; off < 256; off <<= 1) {
            const int mine = s_cnt[tid];
            const int add = (tid >= off) ? s_cnt[tid - off] : 0;
            __syncthreads();
            s_cnt[tid] = mine + add;
            __syncthreads();
        }
        const int incl = s_cnt[tid];
        const int total = s_cnt[255];
        const int suff_after = total - incl;   // valid elems in higher threads

        // Walk my 16 elements newest-to-oldest, assigning global reverse ranks.
        int r = 0;
#pragma unroll
        for (int j = 15; j >= 0; --j) {
            if (valid[j]) {
                const long long rev = count_so_far + suff_after + r;
                if (rev < BUF_SIZE) {
                    const double lp = (double)__log2f(v[j]);
                    sum += lp;
                    sumsq += lp * lp;
                }
                r++;
            }
        }

        count_so_far += total;
        __syncthreads();                 // s_cnt reused next iteration
        if (count_so_far >= BUF_SIZE) break;   // uniform across block
    }

    // Block reduction of sum and sumsq (LDS tree).
    s_red[tid] = sum;
    __syncthreads();
    for (int off = 128; off > 0; off >>= 1) {
        if (tid < off) s_red[tid] += s_red[tid + off];
        __syncthreads();
    }
    const double tsum = s_red[0];
    __syncthreads();
    s_red[tid] = sumsq;
    __syncthreads();
    for (int off = 128; off > 0; off >>= 1) {
        if (tid < off) s_red[tid] += s_red[tid + off];
        __syncthreads();
    }
    const double tsumsq = s_red[0];

    if (tid == 0) {
        const long long count = (count_so_far < BUF_SIZE) ? count_so_far : BUF_SIZE;
        float mean, stdv;
        if (count == 0) {
            mean = 0.0f;
            stdv = 1.0f;
        } else {
            mean = (float)(tsum / (double)count);
            if (count > 1) {
                double var = (tsumsq - tsum * tsum / (double)count) /
                             (double)(count - 1);
                if (var < 0.0) var = 0.0;
                stdv = (float)sqrt(var);
            } else {
                stdv = 1.0f;
            }
        }
        if (stdv < 1e-7f) stdv = 1e-7f;
        const float scale = TARGET_LOG_STD / stdv;
        stats[0] = scale;
        stats[1] = TARGET_LOG_MEAN - mean * scale;
    }
}

// ---------------------------------------------------------------------------
// Kernel 2: monolithic streaming transform — exactly one float4 per thread,
// no loop. Wave churn (block turnover) keeps the memory system saturated;
// this pattern measured ~2x the effective BW of a persistent grid-stride
// loop on this chip (R1 vs R3/R5).
//   out = p>0 ? exp2(log2(p)*scale + bias) : 0
// ---------------------------------------------------------------------------
__global__ void apply_kernel(const float4* __restrict__ in4,
                             float4* __restrict__ out4, long long n4,
                             const float* __restrict__ pitch,
                             float* __restrict__ out, long long n,
                             const float* __restrict__ stats) {
    const float scale = stats[0];
    const float bias = stats[1];
    const long long k = (long long)blockIdx.x * blockDim.x + threadIdx.x;

    if (k < n4) {
        const float4 p = in4[k];
        float4 o;
        o.x = (p.x > 0.0f) ? exp2f(fmaf(__log2f(p.x), scale, bias)) : 0.0f;
        o.y = (p.y > 0.0f) ? exp2f(fmaf(__log2f(p.y), scale, bias)) : 0.0f;
        o.z = (p.z > 0.0f) ? exp2f(fmaf(__log2f(p.z), scale, bias)) : 0.0f;
        o.w = (p.w > 0.0f) ? exp2f(fmaf(__log2f(p.w), scale, bias)) : 0.0f;
        out4[k] = o;
    }

    // Scalar tail (n % 4 != 0): at most 3 elements, block 0 thread 0.
    if (blockIdx.x == 0 && threadIdx.x == 0) {
        for (long long t = n4 << 2; t < n; ++t) {
            const float p = pitch[t];
            out[t] = (p > 0.0f) ? exp2f(fmaf(__log2f(p), scale, bias)) : 0.0f;
        }
    }
}

extern "C" void kernel_launch(void* const* d_in, const int* in_sizes, int n_in,
                              void* d_out, int out_size, void* d_ws, size_t ws_size,
                              hipStream_t stream) {
    const float* pitch = (const float*)d_in[0];
    float* out = (float*)d_out;
    const long long n = (long long)in_sizes[0];
    float* stats = (float*)d_ws;   // [0]=scale, [1]=bias

    stats_kernel<<<1, 256, 0, stream>>>(pitch, n, stats);

    const long long n4 = n >> 2;
    long long blocks = (n4 + 255) / 256;   // n=2^25 -> 32768 blocks
    if (blocks < 1) blocks = 1;
    apply_kernel<<<(int)blocks, 256, 0, stream>>>(
        (const float4*)pitch, (float4*)out, n4, pitch, out, n, stats);
}